// Round 1
// baseline (5724.491 us; speedup 1.0000x reference)
//
#include <hip/hip_runtime.h>

#define N_NODES 20000
#define N_EDGES 320000
#define HIDDEN 256
#define N_GRAPHS 64
#define IN_DIM 3
#define OUT_DIM 2

// ---------------- degree / norm ----------------
__global__ void k_degree(const int* __restrict__ dst, float* __restrict__ deg) {
    int e = blockIdx.x * blockDim.x + threadIdx.x;
    if (e < N_EDGES) atomicAdd(&deg[dst[e]], 1.0f);
}

__global__ void k_dinv(float* deg_dinv) {
    int i = blockIdx.x * blockDim.x + threadIdx.x;
    if (i < N_NODES) deg_dinv[i] = rsqrtf(deg_dinv[i] + 1.0f); // +1 self-loop
}

// ---------------- layer 1 input GEMM (IN_DIM=3) ----------------
__global__ void k_lin1(const float* __restrict__ x, const float* __restrict__ W,
                       float* __restrict__ h) {
    int i = blockIdx.x;
    int j = threadIdx.x;
    float x0 = x[i * 3 + 0], x1 = x[i * 3 + 1], x2 = x[i * 3 + 2];
    h[i * HIDDEN + j] = x0 * W[j] + x1 * W[HIDDEN + j] + x2 * W[2 * HIDDEN + j];
}

// ---------------- agg init: bias + self-loop contribution ----------------
__global__ void k_selfbias(const float* __restrict__ h, const float* __restrict__ dinv,
                           const float* __restrict__ b, float* __restrict__ agg) {
    int i = blockIdx.x;
    int j = threadIdx.x;
    float di = dinv[i];
    agg[i * HIDDEN + j] = b[j] + h[i * HIDDEN + j] * di * di;
}

// ---------------- edge scatter: one wave per edge ----------------
__global__ void k_edges(const float* __restrict__ h, const float* __restrict__ dinv,
                        const int* __restrict__ src, const int* __restrict__ dst,
                        float* __restrict__ agg) {
    int e = blockIdx.x * 4 + (threadIdx.x >> 6);
    if (e >= N_EDGES) return;
    int lane = threadIdx.x & 63;
    int s = src[e], d = dst[e];
    float w = dinv[s] * dinv[d];
    float4 v = *reinterpret_cast<const float4*>(h + s * HIDDEN + lane * 4);
    float* out = agg + d * HIDDEN + lane * 4;
    atomicAdd(out + 0, v.x * w);
    atomicAdd(out + 1, v.y * w);
    atomicAdd(out + 2, v.z * w);
    atomicAdd(out + 3, v.w * w);
}

// ---------------- 256x256 GEMM, 8 rows per block, optional input ReLU ----------------
template <bool RELU>
__global__ void k_gemm(const float* __restrict__ in, const float* __restrict__ W,
                       float* __restrict__ out) {
    __shared__ float At[8][HIDDEN];
    int i0 = blockIdx.x * 8;
    int j = threadIdx.x;
#pragma unroll
    for (int r = 0; r < 8; ++r) {
        float v = in[(i0 + r) * HIDDEN + j];
        At[r][j] = RELU ? fmaxf(v, 0.0f) : v;
    }
    __syncthreads();
    float acc[8] = {0, 0, 0, 0, 0, 0, 0, 0};
    for (int k = 0; k < HIDDEN; k += 4) {
        float w0 = W[(k + 0) * HIDDEN + j];
        float w1 = W[(k + 1) * HIDDEN + j];
        float w2 = W[(k + 2) * HIDDEN + j];
        float w3 = W[(k + 3) * HIDDEN + j];
#pragma unroll
        for (int r = 0; r < 8; ++r) {
            float4 a = *reinterpret_cast<const float4*>(&At[r][k]);
            acc[r] = fmaf(a.x, w0, acc[r]);
            acc[r] = fmaf(a.y, w1, acc[r]);
            acc[r] = fmaf(a.z, w2, acc[r]);
            acc[r] = fmaf(a.w, w3, acc[r]);
        }
    }
#pragma unroll
    for (int r = 0; r < 8; ++r) out[(i0 + r) * HIDDEN + j] = acc[r];
}

// ---------------- pooling: 32 sorted nodes per block, run-length accumulate ----------------
__global__ void k_pool(const float* __restrict__ agg, const int* __restrict__ batch,
                       float* __restrict__ pooled) {
    int base = blockIdx.x * 32;
    int j = threadIdx.x;
    float acc = 0.0f;
    int cur = batch[base];
    for (int r = 0; r < 32; ++r) {
        int i = base + r;
        if (i >= N_NODES) break;
        int bg = batch[i];
        if (bg != cur) {
            atomicAdd(&pooled[cur * HIDDEN + j], acc);
            acc = 0.0f;
            cur = bg;
        }
        acc += fmaxf(agg[i * HIDDEN + j], 0.0f);
    }
    atomicAdd(&pooled[cur * HIDDEN + j], acc);
}

// ---------------- final linear: [64,256]@[256,2] ----------------
__global__ void k_final(const float* __restrict__ pooled, const float* __restrict__ Wlin,
                        const float* __restrict__ blin, float* __restrict__ out) {
    int t = threadIdx.x; // 0..127
    int g = t >> 1, o = t & 1;
    float s = blin[o];
    for (int k = 0; k < HIDDEN; ++k) s += pooled[g * HIDDEN + k] * Wlin[k * OUT_DIM + o];
    out[g * OUT_DIM + o] = s;
}

extern "C" void kernel_launch(void* const* d_in, const int* in_sizes, int n_in,
                              void* d_out, int out_size, void* d_ws, size_t ws_size,
                              hipStream_t stream) {
    const float* x    = (const float*)d_in[0];
    const int*   esrc = (const int*)d_in[1];
    const int*   edst = esrc + N_EDGES;
    const int*   batch = (const int*)d_in[2];
    const float* W1 = (const float*)d_in[3];
    const float* b1 = (const float*)d_in[4];
    const float* W2 = (const float*)d_in[5];
    const float* b2 = (const float*)d_in[6];
    const float* W3 = (const float*)d_in[7];
    const float* b3 = (const float*)d_in[8];
    const float* W4 = (const float*)d_in[9];
    const float* b4 = (const float*)d_in[10];
    const float* W5 = (const float*)d_in[11];
    const float* b5 = (const float*)d_in[12];
    const float* Wlin = (const float*)d_in[13];
    const float* blin = (const float*)d_in[14];
    float* out = (float*)d_out;

    char* ws = (char*)d_ws;
    const size_t off_dinv   = 0;                       // 20000 f32
    const size_t off_hA     = 80128;                   // 20000*256 f32
    const size_t off_hB     = off_hA + (size_t)N_NODES * HIDDEN * 4;
    const size_t off_pooled = off_hB + (size_t)N_NODES * HIDDEN * 4;

    float* dinv   = (float*)(ws + off_dinv);
    float* hA     = (float*)(ws + off_hA);
    float* hB     = (float*)(ws + off_hB);
    float* pooled = (float*)(ws + off_pooled);

    hipMemsetAsync(dinv, 0, N_NODES * sizeof(float), stream);
    hipMemsetAsync(pooled, 0, N_GRAPHS * HIDDEN * sizeof(float), stream);

    k_degree<<<(N_EDGES + 255) / 256, 256, 0, stream>>>(edst, dinv);
    k_dinv<<<(N_NODES + 255) / 256, 256, 0, stream>>>(dinv);

    const float* Ws[5] = {W1, W2, W3, W4, W5};
    const float* bs[5] = {b1, b2, b3, b4, b5};

    // layer 1
    k_lin1<<<N_NODES, HIDDEN, 0, stream>>>(x, W1, hA);
    k_selfbias<<<N_NODES, HIDDEN, 0, stream>>>(hA, dinv, b1, hB);
    k_edges<<<(N_EDGES + 3) / 4, 256, 0, stream>>>(hA, dinv, esrc, edst, hB);

    // layers 2..5
    for (int l = 1; l < 5; ++l) {
        k_gemm<true><<<N_NODES / 8, HIDDEN, 0, stream>>>(hB, Ws[l], hA);
        k_selfbias<<<N_NODES, HIDDEN, 0, stream>>>(hA, dinv, bs[l], hB);
        k_edges<<<(N_EDGES + 3) / 4, 256, 0, stream>>>(hA, dinv, esrc, edst, hB);
    }

    k_pool<<<N_NODES / 32, HIDDEN, 0, stream>>>(hB, batch, pooled);
    k_final<<<1, 128, 0, stream>>>(pooled, Wlin, blin, out);
}

// Round 2
// 561.155 us; speedup vs baseline: 10.2013x; 10.2013x over previous
//
#include <hip/hip_runtime.h>

#define N_NODES 20000
#define N_EDGES 320000
#define HIDDEN 256
#define N_GRAPHS 64
#define OUT_DIM 2

// ---------------- int degree histogram ----------------
__global__ void k_degree(const int* __restrict__ dst, int* __restrict__ degi) {
    int e = blockIdx.x * blockDim.x + threadIdx.x;
    if (e < N_EDGES) atomicAdd(&degi[dst[e]], 1);
}

__global__ void k_dinv(const int* __restrict__ degi, float* __restrict__ dinv) {
    int i = blockIdx.x * blockDim.x + threadIdx.x;
    if (i < N_NODES) dinv[i] = rsqrtf((float)degi[i] + 1.0f); // +1 self-loop
}

// ---------------- exclusive scan of degrees -> rowptr (+mutable copy) ----------------
// one block, 1024 threads, 20 nodes per thread (1000 active threads)
__global__ void k_scan(const int* __restrict__ degi, int* __restrict__ rowptr,
                       int* __restrict__ rowstart) {
    __shared__ int sums[1024];
    int t = threadIdx.x;
    int base = t * 20;
    int ld[20];
    int local = 0;
    if (t < 1000) {
#pragma unroll
        for (int i = 0; i < 20; ++i) { ld[i] = degi[base + i]; local += ld[i]; }
    }
    sums[t] = local;
    __syncthreads();
    for (int off = 1; off < 1024; off <<= 1) {
        int v = (t >= off) ? sums[t - off] : 0;
        __syncthreads();
        sums[t] += v;
        __syncthreads();
    }
    if (t < 1000) {
        int run = (t == 0) ? 0 : sums[t - 1];
#pragma unroll
        for (int i = 0; i < 20; ++i) {
            rowptr[base + i] = run;
            rowstart[base + i] = run;
            run += ld[i];
        }
    }
    if (t == 1023) rowptr[N_NODES] = sums[1023];
}

// ---------------- CSR fill: slot via int atomic on rowstart ----------------
__global__ void k_fill(const int* __restrict__ src, const int* __restrict__ dst,
                       const float* __restrict__ dinv, int* __restrict__ rowstart,
                       int2* __restrict__ csr) {
    int e = blockIdx.x * blockDim.x + threadIdx.x;
    if (e >= N_EDGES) return;
    int s = src[e], d = dst[e];
    int pos = atomicAdd(&rowstart[d], 1);
    csr[pos] = make_int2(s, __float_as_int(dinv[s] * dinv[d]));
}

// ---------------- layer 1 input GEMM (IN_DIM=3) ----------------
__global__ void k_lin1(const float* __restrict__ x, const float* __restrict__ W,
                       float* __restrict__ h) {
    int i = blockIdx.x;
    int j = threadIdx.x;
    float x0 = x[i * 3 + 0], x1 = x[i * 3 + 1], x2 = x[i * 3 + 2];
    h[i * HIDDEN + j] = x0 * W[j] + x1 * W[HIDDEN + j] + x2 * W[2 * HIDDEN + j];
}

// ---------------- gather aggregation: one wave per node ----------------
__global__ void k_csr_agg(const float* __restrict__ h, const float* __restrict__ dinv,
                          const int* __restrict__ rowptr, const int2* __restrict__ csr,
                          const float* __restrict__ b, float* __restrict__ out) {
    int node = blockIdx.x * 4 + (threadIdx.x >> 6);
    if (node >= N_NODES) return;
    int lane = threadIdx.x & 63;
    int beg = rowptr[node], end = rowptr[node + 1];
    float di = dinv[node];
    float w0 = di * di;
    float4 bv = *reinterpret_cast<const float4*>(b + lane * 4);
    float4 hv = *reinterpret_cast<const float4*>(h + (size_t)node * HIDDEN + lane * 4);
    float4 acc;
    acc.x = fmaf(hv.x, w0, bv.x);
    acc.y = fmaf(hv.y, w0, bv.y);
    acc.z = fmaf(hv.z, w0, bv.z);
    acc.w = fmaf(hv.w, w0, bv.w);
    for (int k = beg; k < end; ++k) {
        int2 ew = csr[k];
        float w = __int_as_float(ew.y);
        float4 v = *reinterpret_cast<const float4*>(h + (size_t)ew.x * HIDDEN + lane * 4);
        acc.x = fmaf(v.x, w, acc.x);
        acc.y = fmaf(v.y, w, acc.y);
        acc.z = fmaf(v.z, w, acc.z);
        acc.w = fmaf(v.w, w, acc.w);
    }
    *reinterpret_cast<float4*>(out + (size_t)node * HIDDEN + lane * 4) = acc;
}

// ---------------- 256x256 GEMM, 8 rows per block, input ReLU ----------------
template <bool RELU>
__global__ void k_gemm(const float* __restrict__ in, const float* __restrict__ W,
                       float* __restrict__ out) {
    __shared__ float At[8][HIDDEN];
    int i0 = blockIdx.x * 8;
    int j = threadIdx.x;
#pragma unroll
    for (int r = 0; r < 8; ++r) {
        float v = in[(i0 + r) * HIDDEN + j];
        At[r][j] = RELU ? fmaxf(v, 0.0f) : v;
    }
    __syncthreads();
    float acc[8] = {0, 0, 0, 0, 0, 0, 0, 0};
    for (int k = 0; k < HIDDEN; k += 4) {
        float w0 = W[(k + 0) * HIDDEN + j];
        float w1 = W[(k + 1) * HIDDEN + j];
        float w2 = W[(k + 2) * HIDDEN + j];
        float w3 = W[(k + 3) * HIDDEN + j];
#pragma unroll
        for (int r = 0; r < 8; ++r) {
            float4 a = *reinterpret_cast<const float4*>(&At[r][k]);
            acc[r] = fmaf(a.x, w0, acc[r]);
            acc[r] = fmaf(a.y, w1, acc[r]);
            acc[r] = fmaf(a.z, w2, acc[r]);
            acc[r] = fmaf(a.w, w3, acc[r]);
        }
    }
#pragma unroll
    for (int r = 0; r < 8; ++r) out[(i0 + r) * HIDDEN + j] = acc[r];
}

// ---------------- pooling: 32 sorted nodes per block, run-length accumulate ----------------
__global__ void k_pool(const float* __restrict__ agg, const int* __restrict__ batch,
                       float* __restrict__ pooled) {
    int base = blockIdx.x * 32;
    int j = threadIdx.x;
    float acc = 0.0f;
    int cur = batch[base];
    for (int r = 0; r < 32; ++r) {
        int i = base + r;
        if (i >= N_NODES) break;
        int bg = batch[i];
        if (bg != cur) {
            atomicAdd(&pooled[cur * HIDDEN + j], acc);
            acc = 0.0f;
            cur = bg;
        }
        acc += fmaxf(agg[i * HIDDEN + j], 0.0f);
    }
    atomicAdd(&pooled[cur * HIDDEN + j], acc);
}

// ---------------- final linear: [64,256]@[256,2] ----------------
__global__ void k_final(const float* __restrict__ pooled, const float* __restrict__ Wlin,
                        const float* __restrict__ blin, float* __restrict__ out) {
    int t = threadIdx.x; // 0..127
    int g = t >> 1, o = t & 1;
    float s = blin[o];
    for (int k = 0; k < HIDDEN; ++k) s += pooled[g * HIDDEN + k] * Wlin[k * OUT_DIM + o];
    out[g * OUT_DIM + o] = s;
}

extern "C" void kernel_launch(void* const* d_in, const int* in_sizes, int n_in,
                              void* d_out, int out_size, void* d_ws, size_t ws_size,
                              hipStream_t stream) {
    const float* x     = (const float*)d_in[0];
    const int*   esrc  = (const int*)d_in[1];
    const int*   edst  = esrc + N_EDGES;
    const int*   batch = (const int*)d_in[2];
    const float* W1 = (const float*)d_in[3];
    const float* b1 = (const float*)d_in[4];
    const float* W2 = (const float*)d_in[5];
    const float* b2 = (const float*)d_in[6];
    const float* W3 = (const float*)d_in[7];
    const float* b3 = (const float*)d_in[8];
    const float* W4 = (const float*)d_in[9];
    const float* b4 = (const float*)d_in[10];
    const float* W5 = (const float*)d_in[11];
    const float* b5 = (const float*)d_in[12];
    const float* Wlin = (const float*)d_in[13];
    const float* blin = (const float*)d_in[14];
    float* out = (float*)d_out;

    char* ws = (char*)d_ws;
    size_t off = 0;
    auto alloc = [&](size_t bytes) { size_t o = off; off += (bytes + 255) & ~size_t(255); return (void*)(ws + o); };

    int*   degi     = (int*)alloc(N_NODES * 4);
    float* dinv     = (float*)alloc(N_NODES * 4);
    int*   rowptr   = (int*)alloc((N_NODES + 1) * 4);
    int*   rowstart = (int*)alloc(N_NODES * 4);
    int2*  csr      = (int2*)alloc((size_t)N_EDGES * 8);
    float* hA       = (float*)alloc((size_t)N_NODES * HIDDEN * 4);
    float* hB       = (float*)alloc((size_t)N_NODES * HIDDEN * 4);
    float* pooled   = (float*)alloc(N_GRAPHS * HIDDEN * 4);

    hipMemsetAsync(degi, 0, N_NODES * 4, stream);
    hipMemsetAsync(pooled, 0, N_GRAPHS * HIDDEN * 4, stream);

    k_degree<<<(N_EDGES + 255) / 256, 256, 0, stream>>>(edst, degi);
    k_dinv<<<(N_NODES + 255) / 256, 256, 0, stream>>>(degi, dinv);
    k_scan<<<1, 1024, 0, stream>>>(degi, rowptr, rowstart);
    k_fill<<<(N_EDGES + 255) / 256, 256, 0, stream>>>(esrc, edst, dinv, rowstart, csr);

    const float* Ws[5] = {W1, W2, W3, W4, W5};
    const float* bs[5] = {b1, b2, b3, b4, b5};

    // layer 1
    k_lin1<<<N_NODES, HIDDEN, 0, stream>>>(x, W1, hA);
    k_csr_agg<<<N_NODES / 4, 256, 0, stream>>>(hA, dinv, rowptr, csr, b1, hB);

    // layers 2..5
    for (int l = 1; l < 5; ++l) {
        k_gemm<true><<<N_NODES / 8, HIDDEN, 0, stream>>>(hB, Ws[l], hA);
        k_csr_agg<<<N_NODES / 4, 256, 0, stream>>>(hA, dinv, rowptr, csr, bs[l], hB);
    }

    k_pool<<<N_NODES / 32, HIDDEN, 0, stream>>>(hB, batch, pooled);
    k_final<<<1, 128, 0, stream>>>(pooled, Wlin, blin, out);
}